// Round 8
// baseline (429.201 us; speedup 1.0000x reference)
//
#include <hip/hip_runtime.h>
#include <stdint.h>

// ---------------------------------------------------------------------------
// HardBinaryConv, algebraic form.
//   sign(w) = 1 - 2*[w <= 0]   (reference: 2*(w>0)-1)
//   y[n,o,h,w] = scale[o] * T[n,h,w]
//              - 2*scale[o] * sum_{(i,r,s): w[o,i,r,s]<=0} x[n,i,h+r-1,w+s-1]
//   T[n,h,w]   = sum_{r,s} U[n,h+r-1,w+s-1]   (3x3 box, zero-pad)
//   U[n,h,w]   = sum_i x[n,i,h,w]             (channel sum)
// Correction set is empty for uniform*1e-3 weights but handled exactly.
// Traffic floor: read x (103 MB) + write y (103 MB) ~= 33 us at 6.3 TB/s.
//
// Fusion law (R2/R3/R5/R7): serial preludes inside the store kernel lose.
// R6 (split, 176.2us): the residual cost is BETWEEN kernels (2 launch/drain
// boundaries + straggler tails ~10us). This version: ONE persistent kernel,
// grid 1024 = exact co-resident capacity (__launch_bounds__(256,4): 4 blk/CU
// x 256 CU; 17KB LDS < 40KB/blk), producer->consumer handoff via device-scope
// atomic flags in ws (re-zeroed per iteration by a 260-B hipMemsetAsync --
// graph-capture-safe; cooperative launch is NOT, per R4).
//   producers (grid-stride 1824): 1568 U-tiles + 256 wprep. The 49th U-tile
//   block of each n box-filters U[n]->T[n] in LDS, releases tready[n].
//   consumers (grid-stride 8192): spin (s_sleep) on tready[n] & wcnt, then
//   R6's proven yout body (f32x4 NT stores, o = blockIdx&255 fixed).
// Safety: barriers drain vmcnt before each fence+release; every U/T line has
// a single writer and is first-read only after its released flag; dispatch-
// start acquire invalidates prior-iteration L2 copies.
// ---------------------------------------------------------------------------

typedef float f32x4 __attribute__((ext_vector_type(4)));

#define GRID 1024

__global__ __launch_bounds__(256, 4) void mega(
    const float* __restrict__ x, float* __restrict__ U, float* __restrict__ T,
    const float* __restrict__ w, float* __restrict__ scale,
    int* __restrict__ nneg, int* __restrict__ negidx,
    int* __restrict__ ucnt, int* __restrict__ wcnt, int* __restrict__ tready,
    float* __restrict__ out) {
    __shared__ float Ls[16][64];             // stage1 transpose buffer (4 KB)
    __shared__ float Ub[3136];               // one U plane for box (12.25 KB)
    __shared__ float red[4];
    __shared__ int cnt;
    __shared__ int sflag;
    const int t = threadIdx.x;

    // ---------------- producer sweep: 1824 tasks over 1024 blocks ----------
    for (int wb = blockIdx.x; wb < 1824; wb += GRID) {
        if (wb < 1568) {                     // U-tile: (n, tile of 64 pixels)
            const int n    = wb / 49;
            const int tile = wb - n * 49;
            const int g    = t >> 4;         // channel group 0..15
            const int sl   = t & 15;         // pixel slot 0..15
            const int hw4  = tile * 16 + sl;
            const f32x4* xp =
                (const f32x4*)(x + (size_t)(n * 256 + g * 16) * 3136) + hw4;
            f32x4 s = {0.f, 0.f, 0.f, 0.f};
#pragma unroll
            for (int c = 0; c < 16; ++c)     // 784 f32x4 = one channel plane
                s += __builtin_nontemporal_load(xp + c * 784);
            *(f32x4*)&Ls[g][sl * 4] = s;
            __syncthreads();
            if (t < 64) {                    // collapse 16 groups
                float us = 0.f;
#pragma unroll
                for (int g2 = 0; g2 < 16; ++g2) us += Ls[g2][t];
                U[(size_t)n * 3136 + tile * 64 + t] = us;
            }
            __syncthreads();                 // barrier drains vmcnt: U stored
            if (t == 0) {
                __threadfence();             // U visible device-wide
                const int old = atomicAdd(&ucnt[n], 1);
                sflag = (old == 48);         // 49th tile closes n
                if (old == 48) __threadfence();
            }
            __syncthreads();
            if (sflag) {                     // close n: box U[n] -> T[n]
                const f32x4* Un4 = (const f32x4*)(U + (size_t)n * 3136);
                f32x4* Ub4 = (f32x4*)Ub;
                for (int j = t; j < 784; j += 256) Ub4[j] = Un4[j];
                __syncthreads();
                float* Tn = T + (size_t)n * 3136;
                for (int p = t; p < 3136; p += 256) {
                    const int h = p / 56, wc = p - h * 56;
                    float acc = 0.f;
#pragma unroll
                    for (int r = -1; r <= 1; ++r) {
                        const int hh = h + r;
                        if (hh < 0 || hh > 55) continue;
                        const float* row = Ub + hh * 56;
                        if (wc > 0)  acc += row[wc - 1];
                        acc += row[wc];
                        if (wc < 55) acc += row[wc + 1];
                    }
                    Tn[p] = acc;
                }
                __syncthreads();             // drain T stores
                if (t == 0) {
                    __threadfence();
                    __hip_atomic_store(&tready[n], 1, __ATOMIC_RELEASE,
                                       __HIP_MEMORY_SCOPE_AGENT);
                }
            }
        } else {                             // wprep: o = wb - 1568
            const int o = wb - 1568;
            if (t == 0) cnt = 0;
            __syncthreads();
            const float* wp = w + ((size_t)o * 256 + t) * 9;
            float s = 0.f;
#pragma unroll
            for (int k = 0; k < 9; ++k) {
                const float v = wp[k];
                s += fabsf(v);
                if (v <= 0.f) {              // sign would be -1 here (rare)
                    const int slot = atomicAdd(&cnt, 1);
                    negidx[o * 2304 + slot] = t * 9 + k;
                }
            }
#pragma unroll
            for (int off = 32; off > 0; off >>= 1) s += __shfl_down(s, off);
            if ((t & 63) == 0) red[t >> 6] = s;
            __syncthreads();
            if (t == 0) {
                scale[o] = (red[0] + red[1] + red[2] + red[3]) * (1.f / 2304.f);
                nneg[o]  = cnt;
            }
            __syncthreads();                 // drain scale/nneg/negidx
            if (t == 0) {
                __threadfence();
                atomicAdd(wcnt, 1);
            }
        }
        __syncthreads();                     // protect Ls/red reuse next sweep
    }

    // ---------------- consumer sweep: 8192 (n,o) planes --------------------
    bool wdone = false;                      // thread 0 only
    for (int v = blockIdx.x; v < 8192; v += GRID) {
        const int n = v >> 8, o = v & 255;   // o fixed per block (GRID%256==0)
        if (t == 0) {
            while (!__hip_atomic_load(&tready[n], __ATOMIC_ACQUIRE,
                                      __HIP_MEMORY_SCOPE_AGENT))
                __builtin_amdgcn_s_sleep(2);
            if (!wdone) {
                while (__hip_atomic_load(wcnt, __ATOMIC_ACQUIRE,
                                         __HIP_MEMORY_SCOPE_AGENT) < 256)
                    __builtin_amdgcn_s_sleep(2);
                wdone = true;
            }
        }
        __syncthreads();                     // all threads gated
        const float sc = scale[o];
        const int nn = nneg[o];
        const f32x4* Tn = (const f32x4*)(T + (size_t)n * 3136);
        f32x4* op = (f32x4*)(out + ((size_t)n * 256 + o) * 3136);
        if (nn == 0) {                       // uniform fast path
#pragma unroll
            for (int j = 0; j < 4; ++j) {
                const int hw4 = t + j * 256;
                if (hw4 >= 784) break;       // 784 f32x4 = 3136 floats
                f32x4 vv = Tn[hw4] * sc;
                __builtin_nontemporal_store(vv, op + hw4);
            }
        } else {                             // exact sparse correction (rare)
            const float c2 = 2.f * sc;
#pragma unroll
            for (int j = 0; j < 4; ++j) {
                const int hw4 = t + j * 256;
                if (hw4 >= 784) break;
                f32x4 vv = Tn[hw4] * sc;
                for (int q = 0; q < nn; ++q) {
                    const int iof = negidx[o * 2304 + q];
                    const int ic = iof / 9, rs = iof - ic * 9;
                    const int r = rs / 3 - 1, s2 = rs - (rs / 3) * 3 - 1;
                    const float* xpl = x + ((size_t)n * 256 + ic) * 3136;
#pragma unroll
                    for (int e = 0; e < 4; ++e) {
                        const int p = hw4 * 4 + e;
                        const int h = p / 56 + r, ww = p - (p / 56) * 56 + s2;
                        const float xv = (h >= 0 && h < 56 && ww >= 0 && ww < 56)
                                             ? xpl[h * 56 + ww] : 0.f;
                        vv[e] -= c2 * xv;
                    }
                }
                __builtin_nontemporal_store(vv, op + hw4);
            }
        }
    }
}

// ---------------------------------------------------------------------------
extern "C" void kernel_launch(void* const* d_in, const int* in_sizes, int n_in,
                              void* d_out, int out_size, void* d_ws, size_t ws_size,
                              hipStream_t stream) {
    const float* x = (const float*)d_in[0];   // (32,256,56,56) fp32, 103 MB
    const float* w = (const float*)d_in[1];   // (256,256,3,3) fp32, 2.4 MB
    float* out = (float*)d_out;               // (32,256,56,56) fp32, 103 MB

    char* ws = (char*)d_ws;
    size_t off = 0;
    float* U = (float*)(ws + off);            // 32*3136 fp32 = 401 KB
    off += (size_t)32 * 3136 * 4;
    float* T = (float*)(ws + off);            // 32*3136 fp32 = 401 KB
    off += (size_t)32 * 3136 * 4;
    float* scale = (float*)(ws + off);        // 256 fp32
    off += 256 * 4;
    int* nneg = (int*)(ws + off);             // 256 int
    off += 256 * 4;
    int* negidx = (int*)(ws + off);           // 256*2304 int = 2.4 MB
    off += (size_t)256 * 2304 * 4;
    int* flags = (int*)(ws + off);            // ucnt[32] | wcnt[1] | tready[32]
    int* ucnt   = flags;
    int* wcnt   = flags + 32;
    int* tready = flags + 33;

    hipMemsetAsync(flags, 0, 65 * sizeof(int), stream);  // re-arm handoff
    void* null_unused = nullptr; (void)null_unused;
    mega<<<dim3(GRID), 256, 0, stream>>>(x, U, T, w, scale, nneg, negidx,
                                         ucnt, wcnt, tready, out);
}

// Round 9
// 237.522 us; speedup vs baseline: 1.8070x; 1.8070x over previous
//
#include <hip/hip_runtime.h>
#include <stdint.h>

// ---------------------------------------------------------------------------
// HardBinaryConv, algebraic form.
//   sign(w) = 1 - 2*[w <= 0]   (reference: 2*(w>0)-1)
//   y[n,o,h,w] = scale[o] * T[n,h,w]
//              - 2*scale[o] * sum_{(i,r,s): w[o,i,r,s]<=0} x[n,i,h+r-1,w+s-1]
//   T[n,h,w]   = sum_{r,s} U[n,h+r-1,w+s-1]   (3x3 box, zero-pad)
//   U[n,h,w]   = sum_i x[n,i,h,w]             (channel sum)
// Correction set is empty for uniform*1e-3 weights but handled exactly.
// Traffic floor: read x (103 MB) + write y (103 MB) ~= 33 us at 6.3 TB/s.
//
// R8 lessons: (a) fixed harness overhead measured at ~129 us; (b) acquire-
// per-poll spin loops emit buffer_inv per iteration and destroy concurrent
// stream BW (300us kernel at 0.5 TB/s); (c) release/acquire flag handoff is
// CORRECT on this part (passed). R6 residual = 2 launch boundaries (~8-10us).
//
// This version: 2 dispatches.
//   d1 stage1U: x -> U[n][3136] + weight prep  (R6 verbatim, no fences).
//   d2 boxyout (8640 blocks):
//     blocks 0..31:  box-filter U[n] -> T[n] through LDS, then ONE
//                    agent-scope RELEASE store to tready[n] (after
//                    __syncthreads has drained the T stores).
//     blocks 32..:   yout body (R6 verbatim): RELAXED poll on tready[n]
//                    (s_sleep between polls) + a single ACQUIRE re-load,
//                    then scale[o]*T[n] with f32x4 NT stores.
//   Box blocks precede all consumers in queue order and never wait ->
//   no deadlock; consumer spins are hidden under the 8640-block ramp.
// ---------------------------------------------------------------------------

typedef float f32x4 __attribute__((ext_vector_type(4)));

// Stage 1, role A (blocks 0..1567): full 256-channel sums -> U[n][3136].
// Stage 1, role B (blocks 1568..1823): scale[o] = mean|w[o]| + sparse list
// of non-positive weights (block o-1568 owns nneg[o]; no pre-zero needed).
__global__ __launch_bounds__(256) void stage1U(const float* __restrict__ x,
                                               float* __restrict__ U,
                                               const float* __restrict__ w,
                                               float* __restrict__ scale,
                                               int* __restrict__ nneg,
                                               int* __restrict__ negidx) {
    __shared__ float Ls[16][64];             // [g][pixel-float]; f32x4 writes
    __shared__ float red[4];                 // are 2-way bank aliased = free
    __shared__ int cnt;
    const int t = threadIdx.x;
    if (blockIdx.x < 1568) {
        const int b    = blockIdx.x;
        const int n    = b / 49;
        const int tile = b - n * 49;         // 49 tiles * 16 f32x4 = 784
        const int g    = t >> 4;             // 0..15 channel group
        const int sl   = t & 15;             // 0..15 pixel slot
        const int hw4  = tile * 16 + sl;
        const f32x4* xp =
            (const f32x4*)(x + (size_t)(n * 256 + g * 16) * 3136) + hw4;
        f32x4 s = {0.f, 0.f, 0.f, 0.f};
#pragma unroll
        for (int c = 0; c < 16; ++c)         // 784 f32x4 = one 3136-elem plane
            s += __builtin_nontemporal_load(xp + c * 784);
        *(f32x4*)&Ls[g][sl * 4] = s;
        __syncthreads();
        if (t < 64) {                        // column sum over 16 groups
            float us = 0.f;
#pragma unroll
            for (int g2 = 0; g2 < 16; ++g2) us += Ls[g2][t];
            U[(size_t)n * 3136 + tile * 64 + t] = us;  // 256 B coalesced
        }
    } else {
        const int o = blockIdx.x - 1568;
        if (t == 0) cnt = 0;
        __syncthreads();
        const float* wp = w + ((size_t)o * 256 + t) * 9;
        float s = 0.f;
#pragma unroll
        for (int k = 0; k < 9; ++k) {
            const float v = wp[k];
            s += fabsf(v);
            if (v <= 0.f) {                  // sign would be -1 here (rare)
                const int slot = atomicAdd(&cnt, 1);
                negidx[o * 2304 + slot] = t * 9 + k;
            }
        }
#pragma unroll
        for (int off = 32; off > 0; off >>= 1) s += __shfl_down(s, off);
        if ((t & 63) == 0) red[t >> 6] = s;
        __syncthreads();
        if (t == 0) {
            scale[o] = (red[0] + red[1] + red[2] + red[3]) * (1.f / 2304.f);
            nneg[o]  = cnt;
        }
    }
}

// Stage 2: box role (blocks 0..31) + yout role (blocks 32..8223).
__global__ __launch_bounds__(256) void boxyout(const float* __restrict__ U,
                                               float* __restrict__ T,
                                               const float* __restrict__ scale,
                                               const int* __restrict__ nneg,
                                               const int* __restrict__ negidx,
                                               const float* __restrict__ x,
                                               int* __restrict__ tready,
                                               float* __restrict__ out) {
    __shared__ float Ub[3136];               // 12.25 KB (box role only)
    const int t = threadIdx.x;

    if (blockIdx.x < 32) {                   // ---- box role: T[n] ----------
        const int n = blockIdx.x;
        const f32x4* Un4 = (const f32x4*)(U + (size_t)n * 3136);
        f32x4* Ub4 = (f32x4*)Ub;
        for (int j = t; j < 784; j += 256) Ub4[j] = Un4[j];
        __syncthreads();
        float* Tn = T + (size_t)n * 3136;
        for (int p = t; p < 3136; p += 256) {
            const int h = p / 56, wc = p - h * 56;
            float acc = 0.f;
#pragma unroll
            for (int r = -1; r <= 1; ++r) {
                const int hh = h + r;
                if (hh < 0 || hh > 55) continue;
                const float* row = Ub + hh * 56;
                if (wc > 0)  acc += row[wc - 1];
                acc += row[wc];
                if (wc < 55) acc += row[wc + 1];
            }
            Tn[p] = acc;
        }
        __syncthreads();                     // drains all waves' T stores
        if (t == 0)                          // single RELEASE: wbL2 + flag
            __hip_atomic_store(&tready[n], 1, __ATOMIC_RELEASE,
                               __HIP_MEMORY_SCOPE_AGENT);
        return;
    }

    // ---- yout role ---------------------------------------------------------
    const int v = blockIdx.x - 32;
    const int n = v >> 8, o = v & 255;       // o fastest -> T[n] L2-hot
    if (t == 0) {
        while (__hip_atomic_load(&tready[n], __ATOMIC_RELAXED,
                                 __HIP_MEMORY_SCOPE_AGENT) == 0)
            __builtin_amdgcn_s_sleep(1);     // RELAXED poll: no cache inv
        (void)__hip_atomic_load(&tready[n], __ATOMIC_ACQUIRE,
                                __HIP_MEMORY_SCOPE_AGENT);  // one inv
    }
    __syncthreads();                         // all threads gated

    const float sc = scale[o];
    const int nn = nneg[o];
    const f32x4* Tn = (const f32x4*)(T + (size_t)n * 3136);
    f32x4* op = (f32x4*)(out + ((size_t)n * 256 + o) * 3136);
    if (nn == 0) {                           // uniform fast path
#pragma unroll
        for (int j = 0; j < 4; ++j) {
            const int hw4 = t + j * 256;
            if (hw4 >= 784) break;           // 784 f32x4 = 3136 floats
            f32x4 vv = Tn[hw4] * sc;
            __builtin_nontemporal_store(vv, op + hw4);
        }
    } else {                                 // exact sparse correction (rare)
        const float c2 = 2.f * sc;
#pragma unroll
        for (int j = 0; j < 4; ++j) {
            const int hw4 = t + j * 256;
            if (hw4 >= 784) break;
            f32x4 vv = Tn[hw4] * sc;
            for (int q = 0; q < nn; ++q) {
                const int iof = negidx[o * 2304 + q];
                const int ic = iof / 9, rs = iof - ic * 9;
                const int r = rs / 3 - 1, s2 = rs - (rs / 3) * 3 - 1;
                const float* xpl = x + ((size_t)n * 256 + ic) * 3136;
#pragma unroll
                for (int e = 0; e < 4; ++e) {
                    const int p = hw4 * 4 + e;
                    const int h = p / 56 + r, ww = p - (p / 56) * 56 + s2;
                    const float xv = (h >= 0 && h < 56 && ww >= 0 && ww < 56)
                                         ? xpl[h * 56 + ww] : 0.f;
                    vv[e] -= c2 * xv;
                }
            }
            __builtin_nontemporal_store(vv, op + hw4);
        }
    }
}

// ---------------------------------------------------------------------------
extern "C" void kernel_launch(void* const* d_in, const int* in_sizes, int n_in,
                              void* d_out, int out_size, void* d_ws, size_t ws_size,
                              hipStream_t stream) {
    const float* x = (const float*)d_in[0];   // (32,256,56,56) fp32, 103 MB
    const float* w = (const float*)d_in[1];   // (256,256,3,3) fp32, 2.4 MB
    float* out = (float*)d_out;               // (32,256,56,56) fp32, 103 MB

    char* ws = (char*)d_ws;
    size_t off = 0;
    float* U = (float*)(ws + off);            // 32*3136 fp32 = 401 KB
    off += (size_t)32 * 3136 * 4;
    float* T = (float*)(ws + off);            // 32*3136 fp32 = 401 KB
    off += (size_t)32 * 3136 * 4;
    float* scale = (float*)(ws + off);        // 256 fp32
    off += 256 * 4;
    int* nneg = (int*)(ws + off);             // 256 int
    off += 256 * 4;
    int* negidx = (int*)(ws + off);           // 256*2304 int = 2.4 MB
    off += (size_t)256 * 2304 * 4;
    int* tready = (int*)(ws + off);           // 32 int flags

    hipMemsetAsync(tready, 0, 32 * sizeof(int), stream);  // re-arm handoff
    stage1U<<<dim3(1824), 256, 0, stream>>>(x, U, w, scale, nneg, negidx);
    boxyout<<<dim3(8224), 256, 0, stream>>>(U, T, scale, nneg, negidx, x,
                                            tready, out);
}